// Round 3
// baseline (106781.909 us; speedup 1.0000x reference)
//
#include <hip/hip_runtime.h>
#include <stdint.h>

#define SEQ   512
#define BATCH 64
#define INP   64
#define HID   1024
#define NBLK  512
#define NTHR  256   // 4 waves: (u, kh) = (wave&1, wave>>1)

// ---- grid-wide barrier: flag-array, poison-safe, device-scope (verified R1) ----
__device__ __forceinline__ void gbar(uint32_t* flags, uint32_t val, int tid) {
    __syncthreads();
    if (tid == 0) {
        __threadfence();
        __hip_atomic_store(&flags[blockIdx.x], val, __ATOMIC_RELAXED, __HIP_MEMORY_SCOPE_AGENT);
    }
    if (tid < 64) {
        for (;;) {
            bool ok = true;
            #pragma unroll
            for (int i = 0; i < NBLK / 64; ++i) {
                uint32_t v = __hip_atomic_load(&flags[tid + i * 64], __ATOMIC_RELAXED,
                                               __HIP_MEMORY_SCOPE_AGENT);
                ok &= ((uint32_t)(v - val) < 0x10000000u);
            }
            if (__all(ok)) break;
            __builtin_amdgcn_s_sleep(1);
        }
    }
    if (tid == 0) __threadfence();
    __syncthreads();
}

__device__ __forceinline__ float sigf(float x) { return 1.0f / (1.0f + __expf(-x)); }

// dot over h stored [k][b] (stride 64 floats), k in [k0,k1), (k1-k0)%64==0, >=128.
// Ping-pong 32-deep register prefetch; weights broadcast b128 from LDS.
__device__ __forceinline__ void dot_h(const float* __restrict__ hr, int b,
                                      const float (* __restrict__ Wk)[4],
                                      int k0, int k1,
                                      float& a0, float& a1, float& a2, float& a3)
{
    const float* hp = hr + b;
    float A[32], B[32];
    #pragma unroll
    for (int i = 0; i < 32; ++i) A[i] = hp[(k0 + i) * 64];
    int kb = k0;
    for (; kb < k1 - 64; kb += 64) {
        #pragma unroll
        for (int i = 0; i < 32; ++i) B[i] = hp[(kb + 32 + i) * 64];
        #pragma unroll
        for (int i = 0; i < 32; ++i) {
            float4 wv = *(const float4*)&Wk[kb + i][0];
            a0 += wv.x * A[i]; a1 += wv.y * A[i]; a2 += wv.z * A[i]; a3 += wv.w * A[i];
        }
        #pragma unroll
        for (int i = 0; i < 32; ++i) A[i] = hp[(kb + 64 + i) * 64];
        #pragma unroll
        for (int i = 0; i < 32; ++i) {
            float4 wv = *(const float4*)&Wk[kb + 32 + i][0];
            a0 += wv.x * B[i]; a1 += wv.y * B[i]; a2 += wv.z * B[i]; a3 += wv.w * B[i];
        }
    }
    // tail: kb == k1-64, A holds [kb, kb+32)
    #pragma unroll
    for (int i = 0; i < 32; ++i) B[i] = hp[(kb + 32 + i) * 64];
    #pragma unroll
    for (int i = 0; i < 32; ++i) {
        float4 wv = *(const float4*)&Wk[kb + i][0];
        a0 += wv.x * A[i]; a1 += wv.y * A[i]; a2 += wv.z * A[i]; a3 += wv.w * A[i];
    }
    #pragma unroll
    for (int i = 0; i < 32; ++i) {
        float4 wv = *(const float4*)&Wk[kb + 32 + i][0];
        a0 += wv.x * B[i]; a1 += wv.y * B[i]; a2 += wv.z * B[i]; a3 += wv.w * B[i];
    }
}

__device__ __forceinline__ void fma16(const float4 (&X)[4], const float4 (&W)[16],
                                      float& a0, float& a1, float& a2, float& a3) {
    #pragma unroll
    for (int i = 0; i < 4; ++i) {
        const float xa[4] = {X[i].x, X[i].y, X[i].z, X[i].w};
        #pragma unroll
        for (int m = 0; m < 4; ++m) {
            float4 wv = W[i * 4 + m];
            a0 += wv.x * xa[m]; a1 += wv.y * xa[m];
            a2 += wv.z * xa[m]; a3 += wv.w * xa[m];
        }
    }
}

// K=1024 dot: x per-lane-contiguous float4 (256 of them), weights packed [k][4g]
// wave-uniform broadcast float4 from global (pre-packed). Ping-pong both streams.
// Chunk = 4 float4 of x = 16 elements; chunks c = 0,4,8,...,252 (float4 index base).
// Weights for chunk c: wp[c*4 + i], i in 0..15.  (R2 BUG: loop stopped at c=60.)
__device__ __forceinline__ void dot_xw(const float4* __restrict__ xr,
                                       const float4* __restrict__ wp,
                                       float& a0, float& a1, float& a2, float& a3)
{
    float4 XA[4], XB[4], WA[16], WB[16];
    #pragma unroll
    for (int i = 0; i < 4; ++i) XA[i] = xr[i];
    #pragma unroll
    for (int i = 0; i < 16; ++i) WA[i] = wp[i];
    int f = 0;
    for (; f < 248; f += 8) {
        #pragma unroll
        for (int i = 0; i < 4; ++i) XB[i] = xr[f + 4 + i];
        #pragma unroll
        for (int i = 0; i < 16; ++i) WB[i] = wp[(f + 4) * 4 + i];
        fma16(XA, WA, a0, a1, a2, a3);      // chunk f
        #pragma unroll
        for (int i = 0; i < 4; ++i) XA[i] = xr[f + 8 + i];
        #pragma unroll
        for (int i = 0; i < 16; ++i) WA[i] = wp[(f + 8) * 4 + i];
        fma16(XB, WB, a0, a1, a2, a3);      // chunk f+4
    }
    // f == 248: A holds chunk 248; tail chunk 252
    #pragma unroll
    for (int i = 0; i < 4; ++i) XB[i] = xr[252 + i];
    #pragma unroll
    for (int i = 0; i < 16; ++i) WB[i] = wp[252 * 4 + i];
    fma16(XA, WA, a0, a1, a2, a3);          // chunk 248
    fma16(XB, WB, a0, a1, a2, a3);          // chunk 252
}

// pre-pack W_ih1 into ws: Wp[(j*1024 + k)*4 + g] = Wih[(g*1024 + j)*1024 + k]
__global__ void __launch_bounds__(256) pack_wih1(const float* __restrict__ Wih,
                                                 float* __restrict__ Wp) {
    int idx = blockIdx.x * 256 + threadIdx.x;    // over j*1024 + k, 1M total
    int j = idx >> 10, k = idx & 1023;
    float4 v;
    v.x = Wih[((size_t)(0 * HID + j)) * HID + k];
    v.y = Wih[((size_t)(1 * HID + j)) * HID + k];
    v.z = Wih[((size_t)(2 * HID + j)) * HID + k];
    v.w = Wih[((size_t)(3 * HID + j)) * HID + k];
    *(float4*)&Wp[(size_t)idx * 4] = v;
}

// ================= Phase A: layer-0 scan =================
__global__ void __launch_bounds__(NTHR, 2) lstm_phaseA(
    const float* __restrict__ x,   const float* __restrict__ Wih,
    const float* __restrict__ Whh, const float* __restrict__ bih,
    const float* __restrict__ bhh, float* __restrict__ out,
    float* __restrict__ hbuf, uint32_t* __restrict__ flags)
{
    __shared__ float Wh[2][HID][4];    // 32 KB
    __shared__ float Wi[2][INP][4];    // 2 KB
    __shared__ float red[2][4][64];    // 2 KB
    const int tid = threadIdx.x, bk = blockIdx.x;
    const int w = tid >> 6, b = tid & 63;
    const int u = w & 1, kh = w >> 1;
    const int j = bk * 2 + u;

    for (int idx = tid; idx < 2 * 4 * HID; idx += NTHR) {
        int uu = idx >> 12, rem = idx & 4095, g = rem >> 10, k = rem & 1023;
        Wh[uu][k][g] = Whh[((size_t)(g * HID + bk * 2 + uu)) * HID + k];
    }
    for (int idx = tid; idx < 2 * 4 * INP; idx += NTHR) {
        int uu = idx >> 8, rem = idx & 255, g = rem >> 6, k = rem & 63;
        Wi[uu][k][g] = Wih[(size_t)(g * HID + bk * 2 + uu) * INP + k];
    }
    float bias[4];
    #pragma unroll
    for (int g = 0; g < 4; ++g) bias[g] = bih[g * HID + j] + bhh[g * HID + j];

    if (w < 2) hbuf[j * 64 + b] = 0.0f;   // h(-1)=0 in buffer 0
    float c = 0.0f;
    gbar(flags, 1u, tid);

    for (int t = 0; t < SEQ; ++t) {
        const float* hr = hbuf + (t & 1) * (HID * 64);
        float*       hw = hbuf + ((t & 1) ^ 1) * (HID * 64);
        float a0, a1, a2, a3;
        if (kh == 0) {
            a0 = bias[0]; a1 = bias[1]; a2 = bias[2]; a3 = bias[3];
            const float4* xr = (const float4*)(x + ((size_t)t * BATCH + b) * INP);
            float4 X[16];
            #pragma unroll
            for (int i = 0; i < 16; ++i) X[i] = xr[i];
            #pragma unroll
            for (int i = 0; i < 16; ++i) {
                const float xa[4] = {X[i].x, X[i].y, X[i].z, X[i].w};
                #pragma unroll
                for (int m = 0; m < 4; ++m) {
                    float4 wv = *(const float4*)&Wi[u][i * 4 + m][0];
                    a0 += wv.x * xa[m]; a1 += wv.y * xa[m];
                    a2 += wv.z * xa[m]; a3 += wv.w * xa[m];
                }
            }
            dot_h(hr, b, Wh[u], 0, 512, a0, a1, a2, a3);
        } else {
            a0 = a1 = a2 = a3 = 0.0f;
            dot_h(hr, b, Wh[u], 512, 1024, a0, a1, a2, a3);
            red[u][0][b] = a0; red[u][1][b] = a1; red[u][2][b] = a2; red[u][3][b] = a3;
        }
        __syncthreads();
        if (kh == 0) {
            a0 += red[u][0][b]; a1 += red[u][1][b]; a2 += red[u][2][b]; a3 += red[u][3][b];
            float ig = sigf(a0), fg = sigf(a1), gg = tanhf(a2), og = sigf(a3);
            c = fg * c + ig * gg;
            float h = og * tanhf(c);
            hw[j * 64 + b] = h;
            out[((size_t)t * BATCH + b) * HID + j] = h;   // park h1 in d_out
        }
        if (t < SEQ - 1) gbar(flags, (uint32_t)(t + 2), tid);
    }
}

// ================= Phase B: layer-1 scan + y_pred =================
__global__ void __launch_bounds__(NTHR, 2) lstm_phaseB(
    const float* __restrict__ Whh, const float* __restrict__ bih,
    const float* __restrict__ bhh, const float* __restrict__ Wlin,
    const float* __restrict__ blin, const float* __restrict__ Wp,
    float* __restrict__ out, float* __restrict__ hbuf, uint32_t* __restrict__ flags)
{
    __shared__ float Wh[2][HID][4];    // 32 KB (recurrent weights only)
    __shared__ float red[2][4][64];    // 2 KB
    const int tid = threadIdx.x, bk = blockIdx.x;
    const int w = tid >> 6, b = tid & 63;
    const int u = w & 1, kh = w >> 1;
    const int j = bk * 2 + u;

    for (int idx = tid; idx < 2 * 4 * HID; idx += NTHR) {
        int uu = idx >> 12, rem = idx & 4095, g = rem >> 10, k = rem & 1023;
        Wh[uu][k][g] = Whh[((size_t)(g * HID + bk * 2 + uu)) * HID + k];
    }
    float bias[4];
    #pragma unroll
    for (int g = 0; g < 4; ++g) bias[g] = bih[g * HID + j] + bhh[g * HID + j];

    if (w < 2) hbuf[j * 64 + b] = 0.0f;
    float c = 0.0f, hout = 0.0f;
    const float4* wp = (const float4*)(Wp + (size_t)j * 4096);
    gbar(flags, 1u, tid);

    for (int t = 0; t < SEQ; ++t) {
        if (w < 2 && t > 0)    // deferred h2 write (all reads of out[t-1] done at t-1)
            out[((size_t)(t - 1) * BATCH + b) * HID + j] = hout;
        const float* hr = hbuf + (t & 1) * (HID * 64);
        float*       hw = hbuf + ((t & 1) ^ 1) * (HID * 64);
        float a0, a1, a2, a3;
        if (kh == 0) {
            a0 = bias[0]; a1 = bias[1]; a2 = bias[2]; a3 = bias[3];
            dot_xw((const float4*)(out + ((size_t)t * BATCH + b) * HID), wp,
                   a0, a1, a2, a3);
        } else {
            a0 = a1 = a2 = a3 = 0.0f;
            dot_h(hr, b, Wh[u], 0, 1024, a0, a1, a2, a3);
            red[u][0][b] = a0; red[u][1][b] = a1; red[u][2][b] = a2; red[u][3][b] = a3;
        }
        __syncthreads();
        if (kh == 0) {
            a0 += red[u][0][b]; a1 += red[u][1][b]; a2 += red[u][2][b]; a3 += red[u][3][b];
            float ig = sigf(a0), fg = sigf(a1), gg = tanhf(a2), og = sigf(a3);
            c = fg * c + ig * gg;
            float h = og * tanhf(c);
            hw[j * 64 + b] = h;
            hout = h;
        }
        gbar(flags, (uint32_t)(t + 2), tid);
    }
    if (w < 2) out[((size_t)(SEQ - 1) * BATCH + b) * HID + j] = hout;

    // y_pred = h2[T-1] @ W_lin^T + b_lin  (final h2 is in hbuf buffer 0)
    if (bk == 0 && tid < 64) {
        float acc = blin[0];
        #pragma unroll 8
        for (int k = 0; k < HID; ++k) acc += hbuf[k * 64 + tid] * Wlin[k];
        out[(size_t)SEQ * BATCH * HID + tid] = acc;
    }
}

extern "C" void kernel_launch(void* const* d_in, const int* in_sizes, int n_in,
                              void* d_out, int out_size, void* d_ws, size_t ws_size,
                              hipStream_t stream) {
    const float* x     = (const float*)d_in[0];
    const float* Wih0  = (const float*)d_in[1];
    const float* Whh0  = (const float*)d_in[2];
    const float* bih0  = (const float*)d_in[3];
    const float* bhh0  = (const float*)d_in[4];
    const float* Wih1  = (const float*)d_in[5];
    const float* Whh1  = (const float*)d_in[6];
    const float* bih1  = (const float*)d_in[7];
    const float* bhh1  = (const float*)d_in[8];
    const float* Wlin  = (const float*)d_in[9];
    const float* blin  = (const float*)d_in[10];
    float* out = (float*)d_out;

    float* ws = (float*)d_ws;
    float* hA = ws;                                  // 2*1024*64 floats
    float* hB = ws + 2 * HID * BATCH;                // 2*1024*64 floats
    uint32_t* flagsA = (uint32_t*)(ws + 4 * HID * BATCH);
    uint32_t* flagsB = flagsA + NBLK;
    float* Wp = (float*)(flagsB + NBLK);             // 4M floats = 16 MB packed W_ih1

    pack_wih1<<<dim3(4096), dim3(256), 0, stream>>>(Wih1, Wp);
    lstm_phaseA<<<dim3(NBLK), dim3(NTHR), 0, stream>>>(
        x, Wih0, Whh0, bih0, bhh0, out, hA, flagsA);
    lstm_phaseB<<<dim3(NBLK), dim3(NTHR), 0, stream>>>(
        Whh1, bih1, bhh1, Wlin, blin, Wp, out, hB, flagsB);
}